// Round 10
// baseline (1153.695 us; speedup 1.0000x reference)
//
#include <hip/hip_runtime.h>
#include <math.h>

#define HW 4096

__device__ __forceinline__ float bn_apply(float s, float g, float b, float m, float v) {
    return (s - m) * (g * rsqrtf(v + 1e-5f)) + b;
}

// ---------------------------------------------------------------------------
// Kernel A: conv3x3 (C=128 -> 64) + BN + tanh.
// grid 512 = n(8) * tile(16 of 16x16 px) * ocg(4 of 16 oc). block 256.
// ---------------------------------------------------------------------------
extern "C" __global__ __launch_bounds__(256, 2)
void k_conv1(const float* __restrict__ x, const float* __restrict__ w,
             const float* __restrict__ cb, const float* __restrict__ g,
             const float* __restrict__ be, const float* __restrict__ mu,
             const float* __restrict__ var, float* __restrict__ h1)
{
    __shared__ float xs[2][18][18];
    const int t    = threadIdx.x;
    const int blk  = blockIdx.x;
    const int ocg  = blk & 3;
    const int tile = (blk >> 2) & 15;
    const int n    = blk >> 6;
    const int ty0 = (tile >> 2) << 4, tx0 = (tile & 3) << 4;
    const int py = t >> 4, px = t & 15;
    const int ocbase = ocg << 4;
    const float* xn = x + (size_t)n * 128 * HW;

    float acc[16];
#pragma unroll
    for (int i = 0; i < 16; ++i) acc[i] = 0.f;

    // halo staging geometry (18x18 = 324 elems, <=2 per thread)
    const int r0 = t / 18, c0 = t % 18;
    const int gy0 = ty0 + r0 - 1, gx0 = tx0 + c0 - 1;
    const bool in0 = (gy0 >= 0) & (gy0 < 64) & (gx0 >= 0) & (gx0 < 64);
    const int i1 = t + 256;
    const int r1 = i1 / 18, c1 = i1 % 18;
    const int gy1 = ty0 + r1 - 1, gx1 = tx0 + c1 - 1;
    const bool has1 = t < 68;
    const bool in1 = has1 && ((gy1 >= 0) & (gy1 < 64) & (gx1 >= 0) & (gx1 < 64));
    const int off0 = gy0 * 64 + gx0, off1 = gy1 * 64 + gx1;

    float pv0 = in0 ? xn[off0] : 0.f;
    float pv1 = in1 ? xn[off1] : 0.f;
    xs[0][r0][c0] = pv0;
    if (has1) xs[0][r1][c1] = pv1;
    __syncthreads();

    for (int ic = 0; ic < 128; ++ic) {
        if (ic < 127) {  // prefetch next plane into regs (latency hidden by FMAs)
            const float* xpl = xn + (size_t)(ic + 1) * HW;
            pv0 = in0 ? xpl[off0] : 0.f;
            pv1 = in1 ? xpl[off1] : 0.f;
        }
        const float* xc = &xs[ic & 1][0][0];
        float xv[9];
#pragma unroll
        for (int dy = 0; dy < 3; ++dy)
#pragma unroll
            for (int dx = 0; dx < 3; ++dx)
                xv[dy * 3 + dx] = xc[(py + dy) * 18 + px + dx];
        const float* wp = w + (size_t)ocbase * 1152 + ic * 9;  // uniform -> s_load
#pragma unroll
        for (int oc = 0; oc < 16; ++oc) {
#pragma unroll
            for (int d = 0; d < 9; ++d)
                acc[oc] = fmaf(xv[d], wp[oc * 1152 + d], acc[oc]);
        }
        __syncthreads();
        if (ic < 127) {
            float* xb = &xs[(ic + 1) & 1][0][0];
            xb[r0 * 18 + c0] = pv0;
            if (has1) xb[r1 * 18 + c1] = pv1;
        }
        __syncthreads();
    }

    float* h1p = h1 + (size_t)n * 64 * HW + (ty0 + py) * 64 + tx0 + px;
#pragma unroll
    for (int oc = 0; oc < 16; ++oc) {
        int o = ocbase + oc;
        float s = acc[oc] + cb[o];
        s = bn_apply(s, g[o], be[o], mu[o], var[o]);
        h1p[(size_t)o * HW] = tanhf(s);
    }
}

// ---------------------------------------------------------------------------
// Kernel B: conv3x3 (64 -> 12 ch of one m-group) + BN + tanh + FB projection.
// grid 768 = n(8) * tile(16) * mg(6). block 256.
// writes bases[n][m*25+l][y][x]  (8,150,64,64)
// ---------------------------------------------------------------------------
extern "C" __global__ __launch_bounds__(256, 3)
void k_conv2(const float* __restrict__ h1, const float* __restrict__ w,
             const float* __restrict__ cb, const float* __restrict__ g,
             const float* __restrict__ be, const float* __restrict__ mu,
             const float* __restrict__ var, const float* __restrict__ fb,
             float* __restrict__ bases)
{
    __shared__ float xs[2][18][18];
    const int t    = threadIdx.x;
    const int blk  = blockIdx.x;
    const int mg   = blk % 6;
    const int tile = (blk / 6) & 15;
    const int n    = blk / 96;
    const int ty0 = (tile >> 2) << 4, tx0 = (tile & 3) << 4;
    const int py = t >> 4, px = t & 15;
    const float* hn = h1 + (size_t)n * 64 * HW;

    float acc[12];
#pragma unroll
    for (int i = 0; i < 12; ++i) acc[i] = 0.f;

    const int r0 = t / 18, c0 = t % 18;
    const int gy0 = ty0 + r0 - 1, gx0 = tx0 + c0 - 1;
    const bool in0 = (gy0 >= 0) & (gy0 < 64) & (gx0 >= 0) & (gx0 < 64);
    const int i1 = t + 256;
    const int r1 = i1 / 18, c1 = i1 % 18;
    const int gy1 = ty0 + r1 - 1, gx1 = tx0 + c1 - 1;
    const bool has1 = t < 68;
    const bool in1 = has1 && ((gy1 >= 0) & (gy1 < 64) & (gx1 >= 0) & (gx1 < 64));
    const int off0 = gy0 * 64 + gx0, off1 = gy1 * 64 + gx1;

    float pv0 = in0 ? hn[off0] : 0.f;
    float pv1 = in1 ? hn[off1] : 0.f;
    xs[0][r0][c0] = pv0;
    if (has1) xs[0][r1][c1] = pv1;
    __syncthreads();

    for (int ic = 0; ic < 64; ++ic) {
        if (ic < 63) {
            const float* xpl = hn + (size_t)(ic + 1) * HW;
            pv0 = in0 ? xpl[off0] : 0.f;
            pv1 = in1 ? xpl[off1] : 0.f;
        }
        const float* xc = &xs[ic & 1][0][0];
        float xv[9];
#pragma unroll
        for (int dy = 0; dy < 3; ++dy)
#pragma unroll
            for (int dx = 0; dx < 3; ++dx)
                xv[dy * 3 + dx] = xc[(py + dy) * 18 + px + dx];
        const float* wp = w + (size_t)(mg * 12) * 576 + ic * 9;  // uniform -> s_load
#pragma unroll
        for (int k = 0; k < 12; ++k) {
#pragma unroll
            for (int d = 0; d < 9; ++d)
                acc[k] = fmaf(xv[d], wp[k * 576 + d], acc[k]);
        }
        __syncthreads();
        if (ic < 63) {
            float* xb = &xs[(ic + 1) & 1][0][0];
            xb[r0 * 18 + c0] = pv0;
            if (has1) xb[r1 * 18 + c1] = pv1;
        }
        __syncthreads();
    }

    float tv[12];
#pragma unroll
    for (int k = 0; k < 12; ++k) {
        int o = mg * 12 + k;
        float s = acc[k] + cb[o];
        s = bn_apply(s, g[o], be[o], mu[o], var[o]);
        tv[k] = tanhf(s);
    }
    // FB projection: bases[m][l] = sum_k tv[k] * fb[k][l]
    float* bp = bases + (size_t)n * 150 * HW + (size_t)mg * 25 * HW
              + (ty0 + py) * 64 + tx0 + px;
#pragma unroll
    for (int l = 0; l < 25; ++l) {
        float s = 0.f;
#pragma unroll
        for (int k = 0; k < 12; ++k) s = fmaf(tv[k], fb[k * 25 + l], s);
        bp[(size_t)l * HW] = s;
    }
}

// ---------------------------------------------------------------------------
// Kernel C: per-pixel dynamic filtering + 1x1 conv, fused.
// grid 512 = n(8) * tile(64 of 8x8 px). block 256 (4 waves).
// Per chunk of 8 input channels:
//   T-phase: T[px][c][m] = sum_l P[c,l] * A[m,l]   -> Ts in LDS
//   GEMM:    acc[px][o] += sum_{cm in chunk} coef[o][cm] * Ts[px][cm]
// coef reads are wave-uniform -> scalar loads.
// Ts padded to 53 floats/row: 53 coprime with 32 banks -> 2-way aliasing (free).
// ---------------------------------------------------------------------------
extern "C" __global__ __launch_bounds__(256, 2)
void k_dcf(const float* __restrict__ x, const float* __restrict__ bases,
           const float* __restrict__ coef, const float* __restrict__ bias,
           float* __restrict__ out)
{
    __shared__ float As[150][64];   // A[m*25+l][px]           37.5 KB
    __shared__ float xs[8][12][12]; // x chunk with halo 2      4.5 KB
    __shared__ float Ts[64][53];    // T exchange (48 used)    13.6 KB
    const int t    = threadIdx.x;
    const int blk  = blockIdx.x;
    const int n    = blk >> 6;
    const int tile = blk & 63;
    const int ty0 = (tile >> 3) << 3, tx0 = (tile & 7) << 3;
    const int px = t & 63;        // pixel within 8x8 tile
    const int gq = t >> 6;        // wave id
    const int ppy = px >> 3, ppx = px & 7;
    const float* xn = x + (size_t)n * 128 * HW;

    // stage A (bases) for this tile: As[ml][px]
    {
        const float* bp = bases + (size_t)n * 150 * HW + ty0 * 64 + tx0;
        for (int i = t; i < 9600; i += 256) {
            int ml = i >> 6, p = i & 63;
            As[ml][p] = bp[(size_t)ml * HW + (p >> 3) * 64 + (p & 7)];
        }
    }

    float acc[32];
#pragma unroll
    for (int i = 0; i < 32; ++i) acc[i] = 0.f;

    float pv[5];
    // prefetch chunk 0 (x channels 0..7, 12x12 halo tile)
#pragma unroll
    for (int j = 0; j < 5; ++j) {
        int i = t + j * 256;
        if (i < 1152) {
            int cl = i / 144, rr = (i % 144) / 12, cc = i % 12;
            int gy = ty0 + rr - 2, gx = tx0 + cc - 2;
            bool in = (gy >= 0) & (gy < 64) & (gx >= 0) & (gx < 64);
            pv[j] = in ? xn[(size_t)cl * HW + gy * 64 + gx] : 0.f;
        }
    }
    __syncthreads();  // As visible

    const int wv = __builtin_amdgcn_readfirstlane(t >> 6);

    for (int ch = 0; ch < 16; ++ch) {
        // write staged x chunk to LDS
#pragma unroll
        for (int j = 0; j < 5; ++j) {
            int i = t + j * 256;
            if (i < 1152) (&xs[0][0][0])[i] = pv[j];
        }
        __syncthreads();  // xs ready; also separates prev GEMM (Ts reads) from Ts writes

        // T-phase: this thread handles c_local = gq*2, gq*2+1 for its pixel
        float T[2][6];
#pragma unroll
        for (int a = 0; a < 2; ++a)
#pragma unroll
            for (int m = 0; m < 6; ++m) T[a][m] = 0.f;
        const int c0 = gq * 2;
#pragma unroll
        for (int l = 0; l < 25; ++l) {
            const int dy = l / 5, dx = l % 5;
            float a0 = As[l][px];
            float a1 = As[25 + l][px];
            float a2 = As[50 + l][px];
            float a3 = As[75 + l][px];
            float a4 = As[100 + l][px];
            float a5 = As[125 + l][px];
#pragma unroll
            for (int cl = 0; cl < 2; ++cl) {
                float p = xs[c0 + cl][ppy + dy][ppx + dx];
                T[cl][0] = fmaf(p, a0, T[cl][0]);
                T[cl][1] = fmaf(p, a1, T[cl][1]);
                T[cl][2] = fmaf(p, a2, T[cl][2]);
                T[cl][3] = fmaf(p, a3, T[cl][3]);
                T[cl][4] = fmaf(p, a4, T[cl][4]);
                T[cl][5] = fmaf(p, a5, T[cl][5]);
            }
        }
#pragma unroll
        for (int cl = 0; cl < 2; ++cl)
#pragma unroll
            for (int m = 0; m < 6; ++m)
                Ts[px][(c0 + cl) * 6 + m] = T[cl][m];

        // prefetch next chunk while waiting (hidden under barrier + GEMM)
        if (ch < 15) {
#pragma unroll
            for (int j = 0; j < 5; ++j) {
                int i = t + j * 256;
                if (i < 1152) {
                    int cl = i / 144, rr = (i % 144) / 12, cc = i % 12;
                    int gy = ty0 + rr - 2, gx = tx0 + cc - 2;
                    bool in = (gy >= 0) & (gy < 64) & (gx >= 0) & (gx < 64);
                    pv[j] = in ? xn[(size_t)((ch + 1) * 8 + cl) * HW + gy * 64 + gx] : 0.f;
                }
            }
        }
        __syncthreads();  // Ts ready

        // GEMM: wave wv owns outputs o = wv*32 .. wv*32+31, lane = pixel
        const float* cbp = coef + (size_t)(wv * 32) * 768 + ch * 48;
#pragma unroll
        for (int j = 0; j < 12; ++j) {
            float4 tvv = *(const float4*)&Ts[px][j * 4];
#pragma unroll
            for (int oi = 0; oi < 32; ++oi) {
                float4 cv = *(const float4*)(cbp + (size_t)oi * 768 + j * 4);  // scalar
                acc[oi] = fmaf(tvv.x, cv.x, acc[oi]);
                acc[oi] = fmaf(tvv.y, cv.y, acc[oi]);
                acc[oi] = fmaf(tvv.z, cv.z, acc[oi]);
                acc[oi] = fmaf(tvv.w, cv.w, acc[oi]);
            }
        }
        // no barrier needed here: next xs write + its barrier precede next Ts writes
    }

    float* op = out + (size_t)n * 128 * HW + (ty0 + ppy) * 64 + tx0 + ppx;
#pragma unroll
    for (int oi = 0; oi < 32; ++oi) {
        int o = wv * 32 + oi;
        op[(size_t)o * HW] = acc[oi] + bias[o];
    }
}

// ---------------------------------------------------------------------------
extern "C" void kernel_launch(void* const* d_in, const int* in_sizes, int n_in,
                              void* d_out, int out_size, void* d_ws, size_t ws_size,
                              hipStream_t stream)
{
    const float* x       = (const float*)d_in[0];
    const float* conv1_w = (const float*)d_in[1];
    const float* conv1_b = (const float*)d_in[2];
    const float* bn1_g   = (const float*)d_in[3];
    const float* bn1_b   = (const float*)d_in[4];
    const float* bn1_m   = (const float*)d_in[5];
    const float* bn1_v   = (const float*)d_in[6];
    const float* conv2_w = (const float*)d_in[7];
    const float* conv2_b = (const float*)d_in[8];
    const float* bn2_g   = (const float*)d_in[9];
    const float* bn2_b   = (const float*)d_in[10];
    const float* bn2_m   = (const float*)d_in[11];
    const float* bn2_v   = (const float*)d_in[12];
    const float* fb      = (const float*)d_in[13];
    const float* coef    = (const float*)d_in[14];
    const float* bias    = (const float*)d_in[15];
    float* outp  = (float*)d_out;
    float* h1    = (float*)d_ws;                      // 8*64*4096 floats = 8.39 MB
    float* bases = h1 + (size_t)8 * 64 * 4096;        // 8*150*4096 floats = 19.66 MB

    k_conv1<<<512, 256, 0, stream>>>(x, conv1_w, conv1_b, bn1_g, bn1_b, bn1_m, bn1_v, h1);
    k_conv2<<<768, 256, 0, stream>>>(h1, conv2_w, conv2_b, bn2_g, bn2_b, bn2_m, bn2_v, fb, bases);
    k_dcf<<<512, 256, 0, stream>>>(x, bases, coef, bias, outp);
}

// Round 11
// 749.121 us; speedup vs baseline: 1.5401x; 1.5401x over previous
//
#include <hip/hip_runtime.h>
#include <math.h>

#define HW 4096

__device__ __forceinline__ float bn_apply(float s, float g, float b, float m, float v) {
    return (s - m) * (g * rsqrtf(v + 1e-5f)) + b;
}

// ---------------------------------------------------------------------------
// Kernel A: conv3x3 (C=128 -> 64) + BN + tanh.  (unchanged from validated r10)
// ---------------------------------------------------------------------------
extern "C" __global__ __launch_bounds__(256, 2)
void k_conv1(const float* __restrict__ x, const float* __restrict__ w,
             const float* __restrict__ cb, const float* __restrict__ g,
             const float* __restrict__ be, const float* __restrict__ mu,
             const float* __restrict__ var, float* __restrict__ h1)
{
    __shared__ float xs[2][18][18];
    const int t    = threadIdx.x;
    const int blk  = blockIdx.x;
    const int ocg  = blk & 3;
    const int tile = (blk >> 2) & 15;
    const int n    = blk >> 6;
    const int ty0 = (tile >> 2) << 4, tx0 = (tile & 3) << 4;
    const int py = t >> 4, px = t & 15;
    const int ocbase = ocg << 4;
    const float* xn = x + (size_t)n * 128 * HW;

    float acc[16];
#pragma unroll
    for (int i = 0; i < 16; ++i) acc[i] = 0.f;

    const int r0 = t / 18, c0 = t % 18;
    const int gy0 = ty0 + r0 - 1, gx0 = tx0 + c0 - 1;
    const bool in0 = (gy0 >= 0) & (gy0 < 64) & (gx0 >= 0) & (gx0 < 64);
    const int i1 = t + 256;
    const int r1 = i1 / 18, c1 = i1 % 18;
    const int gy1 = ty0 + r1 - 1, gx1 = tx0 + c1 - 1;
    const bool has1 = t < 68;
    const bool in1 = has1 && ((gy1 >= 0) & (gy1 < 64) & (gx1 >= 0) & (gx1 < 64));
    const int off0 = gy0 * 64 + gx0, off1 = gy1 * 64 + gx1;

    float pv0 = in0 ? xn[off0] : 0.f;
    float pv1 = in1 ? xn[off1] : 0.f;
    xs[0][r0][c0] = pv0;
    if (has1) xs[0][r1][c1] = pv1;
    __syncthreads();

    for (int ic = 0; ic < 128; ++ic) {
        if (ic < 127) {
            const float* xpl = xn + (size_t)(ic + 1) * HW;
            pv0 = in0 ? xpl[off0] : 0.f;
            pv1 = in1 ? xpl[off1] : 0.f;
        }
        const float* xc = &xs[ic & 1][0][0];
        float xv[9];
#pragma unroll
        for (int dy = 0; dy < 3; ++dy)
#pragma unroll
            for (int dx = 0; dx < 3; ++dx)
                xv[dy * 3 + dx] = xc[(py + dy) * 18 + px + dx];
        const float* wp = w + (size_t)ocbase * 1152 + ic * 9;
#pragma unroll
        for (int oc = 0; oc < 16; ++oc) {
#pragma unroll
            for (int d = 0; d < 9; ++d)
                acc[oc] = fmaf(xv[d], wp[oc * 1152 + d], acc[oc]);
        }
        __syncthreads();
        if (ic < 127) {
            float* xb = &xs[(ic + 1) & 1][0][0];
            xb[r0 * 18 + c0] = pv0;
            if (has1) xb[r1 * 18 + c1] = pv1;
        }
        __syncthreads();
    }

    float* h1p = h1 + (size_t)n * 64 * HW + (ty0 + py) * 64 + tx0 + px;
#pragma unroll
    for (int oc = 0; oc < 16; ++oc) {
        int o = ocbase + oc;
        float s = acc[oc] + cb[o];
        s = bn_apply(s, g[o], be[o], mu[o], var[o]);
        h1p[(size_t)o * HW] = tanhf(s);
    }
}

// ---------------------------------------------------------------------------
// Kernel B: conv3x3 (64 -> 12) + BN + tanh + FB projection. (unchanged)
// writes bases[n][m*25+l][y][x]  (8,150,64,64)
// ---------------------------------------------------------------------------
extern "C" __global__ __launch_bounds__(256, 3)
void k_conv2(const float* __restrict__ h1, const float* __restrict__ w,
             const float* __restrict__ cb, const float* __restrict__ g,
             const float* __restrict__ be, const float* __restrict__ mu,
             const float* __restrict__ var, const float* __restrict__ fb,
             float* __restrict__ bases)
{
    __shared__ float xs[2][18][18];
    const int t    = threadIdx.x;
    const int blk  = blockIdx.x;
    const int mg   = blk % 6;
    const int tile = (blk / 6) & 15;
    const int n    = blk / 96;
    const int ty0 = (tile >> 2) << 4, tx0 = (tile & 3) << 4;
    const int py = t >> 4, px = t & 15;
    const float* hn = h1 + (size_t)n * 64 * HW;

    float acc[12];
#pragma unroll
    for (int i = 0; i < 12; ++i) acc[i] = 0.f;

    const int r0 = t / 18, c0 = t % 18;
    const int gy0 = ty0 + r0 - 1, gx0 = tx0 + c0 - 1;
    const bool in0 = (gy0 >= 0) & (gy0 < 64) & (gx0 >= 0) & (gx0 < 64);
    const int i1 = t + 256;
    const int r1 = i1 / 18, c1 = i1 % 18;
    const int gy1 = ty0 + r1 - 1, gx1 = tx0 + c1 - 1;
    const bool has1 = t < 68;
    const bool in1 = has1 && ((gy1 >= 0) & (gy1 < 64) & (gx1 >= 0) & (gx1 < 64));
    const int off0 = gy0 * 64 + gx0, off1 = gy1 * 64 + gx1;

    float pv0 = in0 ? hn[off0] : 0.f;
    float pv1 = in1 ? hn[off1] : 0.f;
    xs[0][r0][c0] = pv0;
    if (has1) xs[0][r1][c1] = pv1;
    __syncthreads();

    for (int ic = 0; ic < 64; ++ic) {
        if (ic < 63) {
            const float* xpl = hn + (size_t)(ic + 1) * HW;
            pv0 = in0 ? xpl[off0] : 0.f;
            pv1 = in1 ? xpl[off1] : 0.f;
        }
        const float* xc = &xs[ic & 1][0][0];
        float xv[9];
#pragma unroll
        for (int dy = 0; dy < 3; ++dy)
#pragma unroll
            for (int dx = 0; dx < 3; ++dx)
                xv[dy * 3 + dx] = xc[(py + dy) * 18 + px + dx];
        const float* wp = w + (size_t)(mg * 12) * 576 + ic * 9;
#pragma unroll
        for (int k = 0; k < 12; ++k) {
#pragma unroll
            for (int d = 0; d < 9; ++d)
                acc[k] = fmaf(xv[d], wp[k * 576 + d], acc[k]);
        }
        __syncthreads();
        if (ic < 63) {
            float* xb = &xs[(ic + 1) & 1][0][0];
            xb[r0 * 18 + c0] = pv0;
            if (has1) xb[r1 * 18 + c1] = pv1;
        }
        __syncthreads();
    }

    float tv[12];
#pragma unroll
    for (int k = 0; k < 12; ++k) {
        int o = mg * 12 + k;
        float s = acc[k] + cb[o];
        s = bn_apply(s, g[o], be[o], mu[o], var[o]);
        tv[k] = tanhf(s);
    }
    float* bp = bases + (size_t)n * 150 * HW + (size_t)mg * 25 * HW
              + (ty0 + py) * 64 + tx0 + px;
#pragma unroll
    for (int l = 0; l < 25; ++l) {
        float s = 0.f;
#pragma unroll
        for (int k = 0; k < 12; ++k) s = fmaf(tv[k], fb[k * 25 + l], s);
        bp[(size_t)l * HW] = s;
    }
}

// ---------------------------------------------------------------------------
// Kernel C1 (NEW): T-phase. T[n][c*6+m][yx] = sum_l patch[c,l]*A[m*25+l].
// A held in 150 REGISTERS per lane (lane = pixel) -> 25 LDS reads feed 150
// FMAs per channel. Single-wave blocks (64 thr), no cross-wave barriers.
// grid 4096 = n(8) x tile(64 of 8x8 px) x cgroup(8 of 16 ch).
// ---------------------------------------------------------------------------
extern "C" __global__ __launch_bounds__(64)
void k_tph(const float* __restrict__ x, const float* __restrict__ bases,
           float* __restrict__ T)
{
    __shared__ float xs[2][4][12][12];   // 2 x 4ch x 12x12 halo = 4.6 KB
    const int t    = threadIdx.x;        // 0..63 = pixel in tile
    const int blk  = blockIdx.x;
    const int cg   = blk & 7;
    const int tile = (blk >> 3) & 63;
    const int n    = blk >> 9;
    const int ty0 = (tile >> 3) << 3, tx0 = (tile & 7) << 3;
    const int ppy = t >> 3, ppx = t & 7;

    // A column for this pixel: 150 registers (statically indexed everywhere)
    float a[150];
    {
        const float* bp = bases + (size_t)n * 150 * HW + (ty0 + ppy) * 64 + (tx0 + ppx);
#pragma unroll
        for (int ml = 0; ml < 150; ++ml) a[ml] = bp[(size_t)ml * HW];
    }

    const float* xc0 = x + ((size_t)n * 128 + cg * 16) * HW;
    float* Tp = T + (size_t)n * 768 * HW + (ty0 + ppy) * 64 + (tx0 + ppx);

    // prefetch chunk 0: 4 channels x 12x12 halo = 576 floats, 9 per lane
    float pv[9];
#pragma unroll
    for (int j = 0; j < 9; ++j) {
        int i = t + j * 64;
        int cl = i / 144, rr = (i % 144) / 12, cc = i % 12;
        int gy = ty0 + rr - 2, gx = tx0 + cc - 2;
        bool in = (gy >= 0) & (gy < 64) & (gx >= 0) & (gx < 64);
        pv[j] = in ? xc0[(size_t)cl * HW + gy * 64 + gx] : 0.f;
    }

    for (int ck = 0; ck < 4; ++ck) {
        float* xb = &xs[ck & 1][0][0][0];
#pragma unroll
        for (int j = 0; j < 9; ++j) xb[t + j * 64] = pv[j];
        if (ck < 3) {   // prefetch next chunk while computing this one
            const float* xn2 = xc0 + (size_t)(ck + 1) * 4 * HW;
#pragma unroll
            for (int j = 0; j < 9; ++j) {
                int i = t + j * 64;
                int cl = i / 144, rr = (i % 144) / 12, cc = i % 12;
                int gy = ty0 + rr - 2, gx = tx0 + cc - 2;
                bool in = (gy >= 0) & (gy < 64) & (gx >= 0) & (gx < 64);
                pv[j] = in ? xn2[(size_t)cl * HW + gy * 64 + gx] : 0.f;
            }
        }
        __syncthreads();  // single wave: cheap; orders ds_write -> ds_read
        const float (*xcur)[12][12] = xs[ck & 1];
#pragma unroll
        for (int cl = 0; cl < 4; ++cl) {
            float wv2[25];
#pragma unroll
            for (int dy = 0; dy < 5; ++dy)
#pragma unroll
                for (int dx = 0; dx < 5; ++dx)
                    wv2[dy * 5 + dx] = xcur[cl][ppy + dy][ppx + dx];
            const int c = cg * 16 + ck * 4 + cl;
#pragma unroll
            for (int m = 0; m < 6; ++m) {
                float s = 0.f;
#pragma unroll
                for (int l = 0; l < 25; ++l) s = fmaf(wv2[l], a[m * 25 + l], s);
                Tp[(size_t)(c * 6 + m) * HW] = s;
            }
        }
    }
}

// ---------------------------------------------------------------------------
// Kernel C2 (NEW): 1x1 conv GEMM. out[n][o][p] = sum_cm coef[o][cm]*T[n][cm][p].
// grid 1024 = n(8) x pblock(64 of 64 contiguous px) x ohalf(2 of 64 o).
// block 256 (4 waves); wave -> 16 outputs, lane = pixel. T chunk (32x64)
// double-buffered in LDS; coef via wave-uniform s_load_dwordx4.
// ---------------------------------------------------------------------------
extern "C" __global__ __launch_bounds__(256)
void k_gemm(const float* __restrict__ T, const float* __restrict__ coef,
            const float* __restrict__ bias, float* __restrict__ out)
{
    __shared__ float Ts[2][32][64];      // 16 KB
    const int t   = threadIdx.x;
    const int blk = blockIdx.x;
    const int oh  = blk & 1;
    const int pb  = (blk >> 1) & 63;
    const int n   = blk >> 7;
    const int px  = t & 63;
    const int wv  = __builtin_amdgcn_readfirstlane(t >> 6);
    const int obase = oh * 64 + wv * 16;

    const float* Tn = T + (size_t)n * 768 * HW + pb * 64;
    const int sr = t >> 3, sc = (t & 7) * 8;   // staging: row sr, cols sc..sc+7

    float4 p0, p1;
    {
        const float* src = Tn + (size_t)sr * HW + sc;
        p0 = *(const float4*)(src);
        p1 = *(const float4*)(src + 4);
    }

    float acc[16];
#pragma unroll
    for (int i = 0; i < 16; ++i) acc[i] = 0.f;

    *(float4*)&Ts[0][sr][sc]     = p0;
    *(float4*)&Ts[0][sr][sc + 4] = p1;
    __syncthreads();

    for (int ch = 0; ch < 24; ++ch) {
        const int cur = ch & 1;
        if (ch < 23) {
            const float* src = Tn + (size_t)((ch + 1) * 32 + sr) * HW + sc;
            p0 = *(const float4*)(src);
            p1 = *(const float4*)(src + 4);
        }
        float tv[32];
#pragma unroll
        for (int k = 0; k < 32; ++k) tv[k] = Ts[cur][k][px];

        const float* cb = coef + (size_t)obase * 768 + ch * 32;
#pragma unroll
        for (int oi = 0; oi < 16; ++oi) {
            const float* cp = cb + (size_t)oi * 768;
#pragma unroll
            for (int kq = 0; kq < 8; ++kq) {
                float4 c4 = *(const float4*)(cp + kq * 4);   // wave-uniform -> s_load
                acc[oi] = fmaf(tv[kq * 4 + 0], c4.x, acc[oi]);
                acc[oi] = fmaf(tv[kq * 4 + 1], c4.y, acc[oi]);
                acc[oi] = fmaf(tv[kq * 4 + 2], c4.z, acc[oi]);
                acc[oi] = fmaf(tv[kq * 4 + 3], c4.w, acc[oi]);
            }
        }
        if (ch < 23) {
            *(float4*)&Ts[cur ^ 1][sr][sc]     = p0;
            *(float4*)&Ts[cur ^ 1][sr][sc + 4] = p1;
        }
        __syncthreads();
    }

    float* op = out + (size_t)n * 128 * HW + pb * 64 + px;
#pragma unroll
    for (int oi = 0; oi < 16; ++oi)
        op[(size_t)(obase + oi) * HW] = acc[oi] + bias[obase + oi];
}

// ---------------------------------------------------------------------------
// FALLBACK (validated r10 fused kernel) — used only if ws too small for T.
// ---------------------------------------------------------------------------
extern "C" __global__ __launch_bounds__(256, 2)
void k_dcf(const float* __restrict__ x, const float* __restrict__ bases,
           const float* __restrict__ coef, const float* __restrict__ bias,
           float* __restrict__ out)
{
    __shared__ float As[150][64];
    __shared__ float xs[8][12][12];
    __shared__ float Ts[64][53];
    const int t    = threadIdx.x;
    const int blk  = blockIdx.x;
    const int n    = blk >> 6;
    const int tile = blk & 63;
    const int ty0 = (tile >> 3) << 3, tx0 = (tile & 7) << 3;
    const int px = t & 63;
    const int gq = t >> 6;
    const int ppy = px >> 3, ppx = px & 7;
    const float* xn = x + (size_t)n * 128 * HW;

    {
        const float* bp = bases + (size_t)n * 150 * HW + ty0 * 64 + tx0;
        for (int i = t; i < 9600; i += 256) {
            int ml = i >> 6, p = i & 63;
            As[ml][p] = bp[(size_t)ml * HW + (p >> 3) * 64 + (p & 7)];
        }
    }

    float acc[32];
#pragma unroll
    for (int i = 0; i < 32; ++i) acc[i] = 0.f;

    float pv[5];
#pragma unroll
    for (int j = 0; j < 5; ++j) {
        int i = t + j * 256;
        if (i < 1152) {
            int cl = i / 144, rr = (i % 144) / 12, cc = i % 12;
            int gy = ty0 + rr - 2, gx = tx0 + cc - 2;
            bool in = (gy >= 0) & (gy < 64) & (gx >= 0) & (gx < 64);
            pv[j] = in ? xn[(size_t)cl * HW + gy * 64 + gx] : 0.f;
        }
    }
    __syncthreads();

    const int wv = __builtin_amdgcn_readfirstlane(t >> 6);

    for (int ch = 0; ch < 16; ++ch) {
#pragma unroll
        for (int j = 0; j < 5; ++j) {
            int i = t + j * 256;
            if (i < 1152) (&xs[0][0][0])[i] = pv[j];
        }
        __syncthreads();

        float T[2][6];
#pragma unroll
        for (int a = 0; a < 2; ++a)
#pragma unroll
            for (int m = 0; m < 6; ++m) T[a][m] = 0.f;
        const int c0 = gq * 2;
#pragma unroll
        for (int l = 0; l < 25; ++l) {
            const int dy = l / 5, dx = l % 5;
            float a0 = As[l][px];
            float a1 = As[25 + l][px];
            float a2 = As[50 + l][px];
            float a3 = As[75 + l][px];
            float a4 = As[100 + l][px];
            float a5 = As[125 + l][px];
#pragma unroll
            for (int cl = 0; cl < 2; ++cl) {
                float p = xs[c0 + cl][ppy + dy][ppx + dx];
                T[cl][0] = fmaf(p, a0, T[cl][0]);
                T[cl][1] = fmaf(p, a1, T[cl][1]);
                T[cl][2] = fmaf(p, a2, T[cl][2]);
                T[cl][3] = fmaf(p, a3, T[cl][3]);
                T[cl][4] = fmaf(p, a4, T[cl][4]);
                T[cl][5] = fmaf(p, a5, T[cl][5]);
            }
        }
#pragma unroll
        for (int cl = 0; cl < 2; ++cl)
#pragma unroll
            for (int m = 0; m < 6; ++m)
                Ts[px][(c0 + cl) * 6 + m] = T[cl][m];

        if (ch < 15) {
#pragma unroll
            for (int j = 0; j < 5; ++j) {
                int i = t + j * 256;
                if (i < 1152) {
                    int cl = i / 144, rr = (i % 144) / 12, cc = i % 12;
                    int gy = ty0 + rr - 2, gx = tx0 + cc - 2;
                    bool in = (gy >= 0) & (gy < 64) & (gx >= 0) & (gx < 64);
                    pv[j] = in ? xn[(size_t)((ch + 1) * 8 + cl) * HW + gy * 64 + gx] : 0.f;
                }
            }
        }
        __syncthreads();

        const float* cbp = coef + (size_t)(wv * 32) * 768 + ch * 48;
#pragma unroll
        for (int j = 0; j < 12; ++j) {
            float4 tvv = *(const float4*)&Ts[px][j * 4];
#pragma unroll
            for (int oi = 0; oi < 32; ++oi) {
                float4 cv = *(const float4*)(cbp + (size_t)oi * 768 + j * 4);
                acc[oi] = fmaf(tvv.x, cv.x, acc[oi]);
                acc[oi] = fmaf(tvv.y, cv.y, acc[oi]);
                acc[oi] = fmaf(tvv.z, cv.z, acc[oi]);
                acc[oi] = fmaf(tvv.w, cv.w, acc[oi]);
            }
        }
    }

    float* op = out + (size_t)n * 128 * HW + (ty0 + ppy) * 64 + tx0 + ppx;
#pragma unroll
    for (int oi = 0; oi < 32; ++oi) {
        int o = wv * 32 + oi;
        op[(size_t)o * HW] = acc[oi] + bias[o];
    }
}

// ---------------------------------------------------------------------------
extern "C" void kernel_launch(void* const* d_in, const int* in_sizes, int n_in,
                              void* d_out, int out_size, void* d_ws, size_t ws_size,
                              hipStream_t stream)
{
    const float* x       = (const float*)d_in[0];
    const float* conv1_w = (const float*)d_in[1];
    const float* conv1_b = (const float*)d_in[2];
    const float* bn1_g   = (const float*)d_in[3];
    const float* bn1_b   = (const float*)d_in[4];
    const float* bn1_m   = (const float*)d_in[5];
    const float* bn1_v   = (const float*)d_in[6];
    const float* conv2_w = (const float*)d_in[7];
    const float* conv2_b = (const float*)d_in[8];
    const float* bn2_g   = (const float*)d_in[9];
    const float* bn2_b   = (const float*)d_in[10];
    const float* bn2_m   = (const float*)d_in[11];
    const float* bn2_v   = (const float*)d_in[12];
    const float* fb      = (const float*)d_in[13];
    const float* coef    = (const float*)d_in[14];
    const float* bias    = (const float*)d_in[15];
    float* outp  = (float*)d_out;
    float* h1    = (float*)d_ws;                       // 8.39 MB
    float* bases = h1 + (size_t)8 * 64 * HW;           // 19.66 MB
    float* Tbuf  = bases + (size_t)8 * 150 * HW;       // 100.66 MB (if it fits)
    const size_t need = ((size_t)8 * 64 * HW + (size_t)8 * 150 * HW
                       + (size_t)8 * 768 * HW) * sizeof(float);

    k_conv1<<<512, 256, 0, stream>>>(x, conv1_w, conv1_b, bn1_g, bn1_b, bn1_m, bn1_v, h1);
    k_conv2<<<768, 256, 0, stream>>>(h1, conv2_w, conv2_b, bn2_g, bn2_b, bn2_m, bn2_v, fb, bases);

    if (ws_size >= need) {
        k_tph <<<4096,  64, 0, stream>>>(x, bases, Tbuf);
        k_gemm<<<1024, 256, 0, stream>>>(Tbuf, coef, bias, outp);
    } else {
        k_dcf <<< 512, 256, 0, stream>>>(x, bases, coef, bias, outp);
    }
}

// Round 12
// 394.955 us; speedup vs baseline: 2.9211x; 1.8967x over previous
//
#include <hip/hip_runtime.h>
#include <math.h>

#define HW 4096

typedef short  bf16x8 __attribute__((ext_vector_type(8)));
typedef float  f32x4  __attribute__((ext_vector_type(4)));

__device__ __forceinline__ float bn_apply(float s, float g, float b, float m, float v) {
    return (s - m) * (g * rsqrtf(v + 1e-5f)) + b;
}

// ---------------------------------------------------------------------------
// coef -> bf16 hi/lo split (truncation split: hi=trunc_bf16(v), lo=trunc_bf16(v-hi))
// ---------------------------------------------------------------------------
extern "C" __global__ __launch_bounds__(256)
void k_cvt(const float* __restrict__ src, unsigned short* __restrict__ hi,
           unsigned short* __restrict__ lo, int nelem)
{
    int i = blockIdx.x * 256 + threadIdx.x;
    if (i < nelem) {
        float v = src[i];
        unsigned u = __float_as_uint(v);
        float hf = __uint_as_float(u & 0xffff0000u);
        float lf = v - hf;
        hi[i] = (unsigned short)(u >> 16);
        lo[i] = (unsigned short)(__float_as_uint(lf) >> 16);
    }
}

// ---------------------------------------------------------------------------
// Kernel A (RESTRUCTURED): conv3x3 (128->64) + BN + tanh.
// 1-wave blocks: 8x8 px tile x 8 oc. grid 4096 = n(8) x tile(64) x ocg(8)
// -> 16 waves/CU (was 8), intra-wave barriers, single barrier per ic.
// ---------------------------------------------------------------------------
extern "C" __global__ __launch_bounds__(64)
void k_conv1(const float* __restrict__ x, const float* __restrict__ w,
             const float* __restrict__ cb, const float* __restrict__ g,
             const float* __restrict__ be, const float* __restrict__ mu,
             const float* __restrict__ var, float* __restrict__ h1)
{
    __shared__ float xs[2][10][10];
    const int t    = threadIdx.x;
    const int blk  = blockIdx.x;
    const int ocg  = blk & 7;
    const int tile = (blk >> 3) & 63;
    const int n    = blk >> 9;
    const int ty0 = (tile >> 3) << 3, tx0 = (tile & 7) << 3;
    const int ppy = t >> 3, ppx = t & 7;
    const int ocbase = ocg << 3;
    const float* xn = x + (size_t)n * 128 * HW;

    float acc[8];
#pragma unroll
    for (int i = 0; i < 8; ++i) acc[i] = 0.f;

    // halo staging: 10x10 = 100 elems, <=2 per thread
    const int r0 = t / 10, c0 = t % 10;
    const int gy0 = ty0 + r0 - 1, gx0 = tx0 + c0 - 1;
    const bool in0 = (gy0 >= 0) & (gy0 < 64) & (gx0 >= 0) & (gx0 < 64);
    const int i1 = t + 64;
    const int r1 = i1 / 10, c1 = i1 % 10;
    const int gy1 = ty0 + r1 - 1, gx1 = tx0 + c1 - 1;
    const bool has1 = t < 36;
    const bool in1 = has1 && ((gy1 >= 0) & (gy1 < 64) & (gx1 >= 0) & (gx1 < 64));
    const int off0 = gy0 * 64 + gx0, off1 = gy1 * 64 + gx1;

    float pv0 = in0 ? xn[off0] : 0.f;
    float pv1 = in1 ? xn[off1] : 0.f;
    xs[0][r0][c0] = pv0;
    if (has1) xs[0][r1][c1] = pv1;
    __syncthreads();

    for (int ic = 0; ic < 128; ++ic) {
        if (ic < 127) {                    // reg-prefetch next plane
            const float* xpl = xn + (size_t)(ic + 1) * HW;
            pv0 = in0 ? xpl[off0] : 0.f;
            pv1 = in1 ? xpl[off1] : 0.f;
        }
        const float* xc = &xs[ic & 1][0][0];
        float xv[9];
#pragma unroll
        for (int dy = 0; dy < 3; ++dy)
#pragma unroll
            for (int dx = 0; dx < 3; ++dx)
                xv[dy * 3 + dx] = xc[(ppy + dy) * 10 + ppx + dx];
        const float* wp = w + (size_t)ocbase * 1152 + ic * 9;   // uniform -> s_load
#pragma unroll
        for (int oc = 0; oc < 8; ++oc) {
#pragma unroll
            for (int d = 0; d < 9; ++d)
                acc[oc] = fmaf(xv[d], wp[oc * 1152 + d], acc[oc]);
        }
        if (ic < 127) {                    // write OTHER buffer (disjoint -> 1 barrier)
            float* xb = &xs[(ic + 1) & 1][0][0];
            xb[r0 * 10 + c0] = pv0;
            if (has1) xb[r1 * 10 + c1] = pv1;
        }
        __syncthreads();
    }

    float* h1p = h1 + (size_t)n * 64 * HW + (ty0 + ppy) * 64 + tx0 + ppx;
#pragma unroll
    for (int oc = 0; oc < 8; ++oc) {
        int o = ocbase + oc;
        float s = acc[oc] + cb[o];
        s = bn_apply(s, g[o], be[o], mu[o], var[o]);
        h1p[(size_t)o * HW] = tanhf(s);
    }
}

// ---------------------------------------------------------------------------
// Kernel B: conv3x3 (64 -> 12) + BN + tanh + FB projection. (unchanged, validated)
// ---------------------------------------------------------------------------
extern "C" __global__ __launch_bounds__(256, 3)
void k_conv2(const float* __restrict__ h1, const float* __restrict__ w,
             const float* __restrict__ cb, const float* __restrict__ g,
             const float* __restrict__ be, const float* __restrict__ mu,
             const float* __restrict__ var, const float* __restrict__ fb,
             float* __restrict__ bases)
{
    __shared__ float xs[2][18][18];
    const int t    = threadIdx.x;
    const int blk  = blockIdx.x;
    const int mg   = blk % 6;
    const int tile = (blk / 6) & 15;
    const int n    = blk / 96;
    const int ty0 = (tile >> 2) << 4, tx0 = (tile & 3) << 4;
    const int py = t >> 4, px = t & 15;
    const float* hn = h1 + (size_t)n * 64 * HW;

    float acc[12];
#pragma unroll
    for (int i = 0; i < 12; ++i) acc[i] = 0.f;

    const int r0 = t / 18, c0 = t % 18;
    const int gy0 = ty0 + r0 - 1, gx0 = tx0 + c0 - 1;
    const bool in0 = (gy0 >= 0) & (gy0 < 64) & (gx0 >= 0) & (gx0 < 64);
    const int i1 = t + 256;
    const int r1 = i1 / 18, c1 = i1 % 18;
    const int gy1 = ty0 + r1 - 1, gx1 = tx0 + c1 - 1;
    const bool has1 = t < 68;
    const bool in1 = has1 && ((gy1 >= 0) & (gy1 < 64) & (gx1 >= 0) & (gx1 < 64));
    const int off0 = gy0 * 64 + gx0, off1 = gy1 * 64 + gx1;

    float pv0 = in0 ? hn[off0] : 0.f;
    float pv1 = in1 ? hn[off1] : 0.f;
    xs[0][r0][c0] = pv0;
    if (has1) xs[0][r1][c1] = pv1;
    __syncthreads();

    for (int ic = 0; ic < 64; ++ic) {
        if (ic < 63) {
            const float* xpl = hn + (size_t)(ic + 1) * HW;
            pv0 = in0 ? xpl[off0] : 0.f;
            pv1 = in1 ? xpl[off1] : 0.f;
        }
        const float* xc = &xs[ic & 1][0][0];
        float xv[9];
#pragma unroll
        for (int dy = 0; dy < 3; ++dy)
#pragma unroll
            for (int dx = 0; dx < 3; ++dx)
                xv[dy * 3 + dx] = xc[(py + dy) * 18 + px + dx];
        const float* wp = w + (size_t)(mg * 12) * 576 + ic * 9;
#pragma unroll
        for (int k = 0; k < 12; ++k) {
#pragma unroll
            for (int d = 0; d < 9; ++d)
                acc[k] = fmaf(xv[d], wp[k * 576 + d], acc[k]);
        }
        __syncthreads();
        if (ic < 63) {
            float* xb = &xs[(ic + 1) & 1][0][0];
            xb[r0 * 18 + c0] = pv0;
            if (has1) xb[r1 * 18 + c1] = pv1;
        }
        __syncthreads();
    }

    float tv[12];
#pragma unroll
    for (int k = 0; k < 12; ++k) {
        int o = mg * 12 + k;
        float s = acc[k] + cb[o];
        s = bn_apply(s, g[o], be[o], mu[o], var[o]);
        tv[k] = tanhf(s);
    }
    float* bp = bases + (size_t)n * 150 * HW + (size_t)mg * 25 * HW
              + (ty0 + py) * 64 + tx0 + px;
#pragma unroll
    for (int l = 0; l < 25; ++l) {
        float s = 0.f;
#pragma unroll
        for (int k = 0; k < 12; ++k) s = fmaf(tv[k], fb[k * 25 + l], s);
        bp[(size_t)l * HW] = s;
    }
}

// ---------------------------------------------------------------------------
// Kernel C1: T-phase (unchanged, validated). T[n][c*6+m][yx], fp32.
// ---------------------------------------------------------------------------
extern "C" __global__ __launch_bounds__(64)
void k_tph(const float* __restrict__ x, const float* __restrict__ bases,
           float* __restrict__ T)
{
    __shared__ float xs[2][4][12][12];
    const int t    = threadIdx.x;
    const int blk  = blockIdx.x;
    const int cg   = blk & 7;
    const int tile = (blk >> 3) & 63;
    const int n    = blk >> 9;
    const int ty0 = (tile >> 3) << 3, tx0 = (tile & 7) << 3;
    const int ppy = t >> 3, ppx = t & 7;

    float a[150];
    {
        const float* bp = bases + (size_t)n * 150 * HW + (ty0 + ppy) * 64 + (tx0 + ppx);
#pragma unroll
        for (int ml = 0; ml < 150; ++ml) a[ml] = bp[(size_t)ml * HW];
    }

    const float* xc0 = x + ((size_t)n * 128 + cg * 16) * HW;
    float* Tp = T + (size_t)n * 768 * HW + (ty0 + ppy) * 64 + (tx0 + ppx);

    float pv[9];
#pragma unroll
    for (int j = 0; j < 9; ++j) {
        int i = t + j * 64;
        int cl = i / 144, rr = (i % 144) / 12, cc = i % 12;
        int gy = ty0 + rr - 2, gx = tx0 + cc - 2;
        bool in = (gy >= 0) & (gy < 64) & (gx >= 0) & (gx < 64);
        pv[j] = in ? xc0[(size_t)cl * HW + gy * 64 + gx] : 0.f;
    }

    for (int ck = 0; ck < 4; ++ck) {
        float* xb = &xs[ck & 1][0][0][0];
#pragma unroll
        for (int j = 0; j < 9; ++j) xb[t + j * 64] = pv[j];
        if (ck < 3) {
            const float* xn2 = xc0 + (size_t)(ck + 1) * 4 * HW;
#pragma unroll
            for (int j = 0; j < 9; ++j) {
                int i = t + j * 64;
                int cl = i / 144, rr = (i % 144) / 12, cc = i % 12;
                int gy = ty0 + rr - 2, gx = tx0 + cc - 2;
                bool in = (gy >= 0) & (gy < 64) & (gx >= 0) & (gx < 64);
                pv[j] = in ? xn2[(size_t)cl * HW + gy * 64 + gx] : 0.f;
            }
        }
        __syncthreads();
        const float (*xcur)[12][12] = xs[ck & 1];
#pragma unroll
        for (int cl = 0; cl < 4; ++cl) {
            float wv2[25];
#pragma unroll
            for (int dy = 0; dy < 5; ++dy)
#pragma unroll
                for (int dx = 0; dx < 5; ++dx)
                    wv2[dy * 5 + dx] = xcur[cl][ppy + dy][ppx + dx];
            const int c = cg * 16 + ck * 4 + cl;
#pragma unroll
            for (int m = 0; m < 6; ++m) {
                float s = 0.f;
#pragma unroll
                for (int l = 0; l < 25; ++l) s = fmaf(wv2[l], a[m * 25 + l], s);
                Tp[(size_t)(c * 6 + m) * HW] = s;
            }
        }
    }
}

// ---------------------------------------------------------------------------
// Kernel C2 (NEW): 1x1 conv GEMM via bf16 hi/lo-split MFMA.
// out[o][px] = sum_k coef[o][k] * T[k][px];  a·b ~= ah·bh + ah·bl + al·bh.
// A = coef hi/lo (global, L2-hot): lane reads A[o=obase+(l&15)][k0+8*(l>>4)+j].
// B = T chunk, staged to LDS transposed [px][k] bf16 (row stride 40 shorts,
//     16B aligned): lane reads B[px=pxb+(l&15)][k0+8*(l>>4)+j].
// D (m89-verified): col = lane&15 (=px -> coalesced), row = (lane>>4)*4+reg (=o).
// grid 512 = n(8) x pb(64 of 64 px). block 256: wave wv -> o in [wv*32, wv*32+32).
// ---------------------------------------------------------------------------
extern "C" __global__ __launch_bounds__(256)
void k_gemm_mfma(const float* __restrict__ T, const unsigned short* __restrict__ chi,
                 const unsigned short* __restrict__ clo, const float* __restrict__ bias,
                 float* __restrict__ out)
{
    __shared__ __align__(16) unsigned short lds[2][2][64 * 40];  // [dbuf][hi/lo][px*40+k]
    const int t    = threadIdx.x;
    const int blk  = blockIdx.x;
    const int pb   = blk & 63;
    const int n    = blk >> 6;
    const int lane = t & 63;
    const int wv   = t >> 6;
    const int l15  = lane & 15;
    const int l4   = lane >> 4;

    const float* Tn = T + (size_t)n * 768 * HW + pb * 64;

    // staging role: thread t -> px_s = t>>2 (0..63), kq = t&3 (8-k slot)
    const int px_s = t >> 2, kq = t & 3;

    float pv[8];
#pragma unroll
    for (int j = 0; j < 8; ++j)
        pv[j] = Tn[(size_t)(kq * 8 + j) * HW + px_s];

    f32x4 acc[2][4];
#pragma unroll
    for (int a2 = 0; a2 < 2; ++a2)
#pragma unroll
        for (int p = 0; p < 4; ++p) acc[a2][p] = (f32x4){0.f, 0.f, 0.f, 0.f};

    // stage chunk 0 into buf 0
    {
        bf16x8 hv, lv;
#pragma unroll
        for (int j = 0; j < 8; ++j) {
            unsigned u = __float_as_uint(pv[j]);
            float hf = __uint_as_float(u & 0xffff0000u);
            float lf = pv[j] - hf;
            hv[j] = (short)(u >> 16);
            lv[j] = (short)(__float_as_uint(lf) >> 16);
        }
        *(bf16x8*)&lds[0][0][px_s * 40 + kq * 8] = hv;
        *(bf16x8*)&lds[0][1][px_s * 40 + kq * 8] = lv;
    }
    __syncthreads();

    for (int ch = 0; ch < 24; ++ch) {
        const int cur = ch & 1;
        if (ch < 23) {                       // prefetch next T chunk to regs
#pragma unroll
            for (int j = 0; j < 8; ++j)
                pv[j] = Tn[(size_t)((ch + 1) * 32 + kq * 8 + j) * HW + px_s];
        }
        // A fragments (coef hi/lo) from global (L2-resident, reused by all blocks)
        bf16x8 ah[2], al[2];
#pragma unroll
        for (int ot = 0; ot < 2; ++ot) {
            size_t off = (size_t)(wv * 32 + ot * 16 + l15) * 768 + ch * 32 + 8 * l4;
            ah[ot] = *(const bf16x8*)(chi + off);
            al[ot] = *(const bf16x8*)(clo + off);
        }
        // B fragments from LDS
        bf16x8 bh[4], bl[4];
#pragma unroll
        for (int p = 0; p < 4; ++p) {
            int row = p * 16 + l15;
            bh[p] = *(const bf16x8*)&lds[cur][0][row * 40 + 8 * l4];
            bl[p] = *(const bf16x8*)&lds[cur][1][row * 40 + 8 * l4];
        }
#pragma unroll
        for (int ot = 0; ot < 2; ++ot)
#pragma unroll
            for (int p = 0; p < 4; ++p) {
                acc[ot][p] = __builtin_amdgcn_mfma_f32_16x16x32_bf16(ah[ot], bh[p], acc[ot][p], 0, 0, 0);
                acc[ot][p] = __builtin_amdgcn_mfma_f32_16x16x32_bf16(ah[ot], bl[p], acc[ot][p], 0, 0, 0);
                acc[ot][p] = __builtin_amdgcn_mfma_f32_16x16x32_bf16(al[ot], bh[p], acc[ot][p], 0, 0, 0);
            }
        if (ch < 23) {                        // stage next chunk into other buffer
            bf16x8 hv, lv;
#pragma unroll
            for (int j = 0; j < 8; ++j) {
                unsigned u = __float_as_uint(pv[j]);
                float hf = __uint_as_float(u & 0xffff0000u);
                float lf = pv[j] - hf;
                hv[j] = (short)(u >> 16);
                lv[j] = (short)(__float_as_uint(lf) >> 16);
            }
            *(bf16x8*)&lds[cur ^ 1][0][px_s * 40 + kq * 8] = hv;
            *(bf16x8*)&lds[cur ^ 1][1][px_s * 40 + kq * 8] = lv;
        }
        __syncthreads();
    }

    // epilogue: D[row=o_sub][col=px_sub], o = obase + ot*16 + 4*l4 + reg, px = p*16 + l15
    float* on = out + (size_t)n * 128 * HW + pb * 64;
#pragma unroll
    for (int ot = 0; ot < 2; ++ot) {
        int o0 = wv * 32 + ot * 16 + 4 * l4;
#pragma unroll
        for (int p = 0; p < 4; ++p) {
            int px = p * 16 + l15;
#pragma unroll
            for (int r = 0; r < 4; ++r) {
                int o = o0 + r;
                on[(size_t)o * HW + px] = acc[ot][p][r] + bias[o];
            }
        }
    }
}

// ---------------------------------------------------------------------------
// FALLBACK fused kernel (validated r10) — only if ws too small for T + coef.
// ---------------------------------------------------------------------------
extern "C" __global__ __launch_bounds__(256, 2)
void k_dcf(const float* __restrict__ x, const float* __restrict__ bases,
           const float* __restrict__ coef, const float* __restrict__ bias,
           float* __restrict__ out)
{
    __shared__ float As[150][64];
    __shared__ float xs[8][12][12];
    __shared__ float Ts[64][53];
    const int t    = threadIdx.x;
    const int blk  = blockIdx.x;
    const int n    = blk >> 6;
    const int tile = blk & 63;
    const int ty0 = (tile >> 3) << 3, tx0 = (tile & 7) << 3;
    const int px = t & 63;
    const int gq = t >> 6;
    const int ppy = px >> 3, ppx = px & 7;
    const float* xn = x + (size_t)n * 128 * HW;

    {
        const float* bp = bases + (size_t)n * 150 * HW + ty0 * 64 + tx0;
        for (int i = t; i < 9600; i += 256) {
            int ml = i >> 6, p = i & 63;
            As[ml][p] = bp[(size_t)ml * HW + (p >> 3) * 64 + (p & 7)];
        }
    }

    float acc[32];
#pragma unroll
    for (int i = 0; i < 32; ++i) acc[i] = 0.f;

    float pv[5];
#pragma unroll
    for (int j = 0; j < 5; ++j) {
        int i = t + j * 256;
        if (i < 1152) {
            int cl = i / 144, rr = (i % 144) / 12, cc = i % 12;
            int gy = ty0 + rr - 2, gx = tx0 + cc - 2;
            bool in = (gy >= 0) & (gy < 64) & (gx >= 0) & (gx < 64);
            pv[j] = in ? xn[(size_t)cl * HW + gy * 64 + gx] : 0.f;
        }
    }
    __syncthreads();

    const int wv = __builtin_amdgcn_readfirstlane(t >> 6);

    for (int ch = 0; ch < 16; ++ch) {
#pragma unroll
        for (int j = 0; j < 5; ++j) {
            int i = t + j * 256;
            if (i < 1152) (&xs[0][0][0])[i] = pv[j];
        }
        __syncthreads();

        float T[2][6];
#pragma unroll
        for (int a = 0; a < 2; ++a)
#pragma unroll
            for (int m = 0; m < 6; ++m) T[a][m] = 0.f;
        const int c0 = gq * 2;
#pragma unroll
        for (int l = 0; l < 25; ++l) {
            const int dy = l / 5, dx = l % 5;
            float a0 = As[l][px];
            float a1 = As[25 + l][px];
            float a2 = As[50 + l][px];
            float a3 = As[75 + l][px];
            float a4 = As[100 + l][px];
            float a5 = As[125 + l][px];
#pragma unroll
            for (int cl = 0; cl < 2; ++cl) {
                float p = xs[c0 + cl][ppy + dy][ppx + dx];
                T[cl][0] = fmaf(p, a0, T[cl][0]);
                T[cl][1] = fmaf(p, a1, T[cl][1]);
                T[cl][2] = fmaf(p, a2, T[cl][2]);
                T[cl][3] = fmaf(p, a3, T[cl][3]);
                T[cl][4] = fmaf(p, a4, T[cl][4]);
                T[cl][5] = fmaf(p, a5, T[cl][5]);
            }
        }
#pragma unroll
        for (int cl = 0; cl < 2; ++cl)
#pragma unroll
            for (int m = 0; m < 6; ++m)
                Ts[px][(c0 + cl) * 6 + m] = T[cl][m];

        if (ch < 15) {
#pragma unroll
            for (int j = 0; j < 5; ++j) {
                int i = t + j * 256;
                if (i < 1152) {
                    int cl = i / 144, rr = (i % 144) / 12, cc = i % 12;
                    int gy = ty0 + rr - 2, gx = tx0 + cc - 2;
                    bool in = (gy >= 0) & (gy < 64) & (gx >= 0) & (gx < 64);
                    pv[j] = in ? xn[(size_t)((ch + 1) * 8 + cl) * HW + gy * 64 + gx] : 0.f;
                }
            }
        }
        __syncthreads();

        const float* cbp = coef + (size_t)(wv * 32) * 768 + ch * 48;
#pragma unroll
        for (int j = 0; j < 12; ++j) {
            float4 tvv = *(const float4*)&Ts[px][j * 4];
#pragma unroll
            for (int oi = 0; oi < 32; ++oi) {
                float4 cv = *(const float4*)(cbp + (size_t)oi * 768 + j * 4);
                acc[oi] = fmaf(tvv.x, cv.x, acc[oi]);
                acc[oi] = fmaf(tvv.y, cv.y, acc[oi]);
                acc[oi] = fmaf(tvv.z, cv.z, acc[oi]);
                acc[oi] = fmaf(tvv.w, cv.w, acc[oi]);
            }
        }
    }

    float* op = out + (size_t)n * 128 * HW + (ty0 + ppy) * 64 + tx0 + ppx;
#pragma unroll
    for (int oi = 0; oi < 32; ++oi) {
        int o = wv * 32 + oi;
        op[(size_t)o * HW] = acc[oi] + bias[o];
    }
}

// ---------------------------------------------------------------------------
extern "C" void kernel_launch(void* const* d_in, const int* in_sizes, int n_in,
                              void* d_out, int out_size, void* d_ws, size_t ws_size,
                              hipStream_t stream)
{
    const float* x       = (const float*)d_in[0];
    const float* conv1_w = (const float*)d_in[1];
    const float* conv1_b = (const float*)d_in[2];
    const float* bn1_g   = (const float*)d_in[3];
    const float* bn1_b   = (const float*)d_in[4];
    const float* bn1_m   = (const float*)d_in[5];
    const float* bn1_v   = (const float*)d_in[6];
    const float* conv2_w = (const float*)d_in[7];
    const float* conv2_b = (const float*)d_in[8];
    const float* bn2_g   = (const float*)d_in[9];
    const float* bn2_b   = (const float*)d_in[10];
    const float* bn2_m   = (const float*)d_in[11];
    const float* bn2_v   = (const float*)d_in[12];
    const float* fb      = (const float*)d_in[13];
    const float* coef    = (const float*)d_in[14];
    const float* bias    = (const float*)d_in[15];
    float* outp  = (float*)d_out;

    float* h1    = (float*)d_ws;                         //  8.39 MB
    float* bases = h1 + (size_t)8 * 64 * HW;             // 19.66 MB
    float* Tbuf  = bases + (size_t)8 * 150 * HW;         // 100.66 MB
    unsigned short* chi = (unsigned short*)(Tbuf + (size_t)8 * 768 * HW);  // 196.6 KB
    unsigned short* clo = chi + (size_t)128 * 768;                          // 196.6 KB
    const size_t need = ((size_t)8 * 64 * HW + (size_t)8 * 150 * HW
                       + (size_t)8 * 768 * HW) * sizeof(float)
                      + (size_t)2 * 128 * 768 * sizeof(unsigned short);

    k_conv1<<<4096, 64, 0, stream>>>(x, conv1_w, conv1_b, bn1_g, bn1_b, bn1_m, bn1_v, h1);
    k_conv2<<<768, 256, 0, stream>>>(h1, conv2_w, conv2_b, bn2_g, bn2_b, bn2_m, bn2_v, fb, bases);

    if (ws_size >= need) {
        k_cvt <<<384, 256, 0, stream>>>(coef, chi, clo, 128 * 768);
        k_tph <<<4096, 64, 0, stream>>>(x, bases, Tbuf);
        k_gemm_mfma<<<512, 256, 0, stream>>>(Tbuf, chi, clo, bias, outp);
    } else {
        k_dcf <<<512, 256, 0, stream>>>(x, bases, coef, bias, outp);
    }
}